// Round 9
// baseline (338.520 us; speedup 1.0000x reference)
//
#include <hip/hip_runtime.h>
#include <hip/hip_bf16.h>

#define B_ 8
#define S_ 2048
#define DM 1024
#define H_ 16
#define DH 64
#define DK 384

#define AS3 __attribute__((address_space(3)))
#define AS1 __attribute__((address_space(1)))
typedef unsigned int u32;

typedef __attribute__((ext_vector_type(8))) short bf16x8;
typedef __attribute__((ext_vector_type(4))) float f32x4;

static __device__ __forceinline__ ushort f2b(float f) {
  __hip_bfloat16 h = __float2bfloat16(f);
  return *reinterpret_cast<ushort*>(&h);
}
static __device__ __forceinline__ float b2f(ushort u) {
  __hip_bfloat16 h;
  *reinterpret_cast<ushort*>(&h) = u;
  return __bfloat162float(h);
}

// ---------------- K0: convert X and Wk/Wv/Wb to bf16 (once) --------------------
__global__ __launch_bounds__(256) void k_cvt(
    const float* __restrict__ X, const float* __restrict__ Wk,
    const float* __restrict__ Wv, const float* __restrict__ Wb,
    ushort* __restrict__ Xb, ushort* __restrict__ Wball) {
  const int total = 2097152 + 3 * 131072;
  int c = blockIdx.x * 256 + threadIdx.x;
  const int stride = gridDim.x * 256;
  for (; c < total; c += stride) {
    const float* s;
    ushort* d;
    size_t off;
    if (c < 2097152) { s = X; d = Xb; off = (size_t)c; }
    else {
      int cc = c - 2097152;
      int wsel = cc >> 17;
      off = (size_t)(cc & 131071);
      s = wsel == 0 ? Wk : (wsel == 1 ? Wv : Wb);
      d = Wball + (size_t)wsel * (DM * DM);
    }
    float4 a = *(const float4*)(s + off * 8);
    float4 b = *(const float4*)(s + off * 8 + 4);
    ushort u[8] = { f2b(a.x), f2b(a.y), f2b(a.z), f2b(a.w),
                    f2b(b.x), f2b(b.y), f2b(b.z), f2b(b.w) };
    *(uint4*)(d + off * 8) = *(uint4*)u;
  }
}

// ---------------- K1: projection GEMM  Y = Xb @ Wb^T, dbuf + XCD swizzle -------
__global__ __launch_bounds__(256) void k_proj(
    const ushort* __restrict__ Xb, const ushort* __restrict__ Wball,
    ushort* __restrict__ kvb) {
  __shared__ ushort SH[4 * 8192];              // As[2] | Bs[2]  (64 KB)
  ushort* As = SH;
  ushort* Bs = SH + 2 * 8192;
  const int t = threadIdx.x, lane = t & 63, w = t >> 6;
  const int wm = w >> 1, wn = w & 1;
  const int bid = blockIdx.x + (blockIdx.y << 7) + (blockIdx.z << 10);
  const int c = bid & 7, r = bid >> 3;
  const int xb = c * 16 + (r & 15);
  const int rest = r >> 4;
  const int yb = rest & 7, zb = rest >> 3;
  const int m0 = xb * 128;
  const int n0 = yb * 128;
  const int wsel = zb;
  const ushort* Wmat = Wball + (size_t)wsel * (DM * DM);
  ushort* out = kvb + (size_t)wsel * ((size_t)B_ * H_ * S_ * DH);

  const int rowst = (lane >> 3);
  const int colsw = ((lane & 7) ^ rowst) << 3;

  auto STAGE = [&](int buf, int k0) {
    #pragma unroll
    for (int j = 0; j < 4; j++) {
      int row = (w * 4 + j) * 8 + rowst;
      __builtin_amdgcn_global_load_lds(
          (const AS1 u32*)(Xb + (size_t)(m0 + row) * DM + k0 + colsw),
          (AS3 u32*)(As + buf * 8192 + (w * 4 + j) * 512), 16, 0, 0);
      __builtin_amdgcn_global_load_lds(
          (const AS1 u32*)(Wmat + (size_t)(n0 + row) * DM + k0 + colsw),
          (AS3 u32*)(Bs + buf * 8192 + (w * 4 + j) * 512), 16, 0, 0);
    }
  };

  f32x4 acc[4][4] = {};
  STAGE(0, 0);
  __syncthreads();
  int cur = 0;
  for (int kt = 0; kt < 16; kt++) {
    if (kt < 15) STAGE(cur ^ 1, (kt + 1) * 64);
    const ushort* Ab = As + cur * 8192;
    const ushort* Bb = Bs + cur * 8192;
    #pragma unroll
    for (int kk2 = 0; kk2 < 2; kk2++) {
      const int csw = (((lane >> 4) + 4 * kk2) ^ (lane & 7)) << 3;
      bf16x8 af[4], bfr[4];
      #pragma unroll
      for (int mi = 0; mi < 4; mi++)
        af[mi] = *(const bf16x8*)&Ab[(wm * 64 + mi * 16 + (lane & 15)) * 64 + csw];
      #pragma unroll
      for (int ni = 0; ni < 4; ni++)
        bfr[ni] = *(const bf16x8*)&Bb[(wn * 64 + ni * 16 + (lane & 15)) * 64 + csw];
      #pragma unroll
      for (int mi = 0; mi < 4; mi++)
        #pragma unroll
        for (int ni = 0; ni < 4; ni++)
          acc[mi][ni] = __builtin_amdgcn_mfma_f32_16x16x32_bf16(af[mi], bfr[ni], acc[mi][ni], 0, 0, 0);
    }
    __syncthreads();
    cur ^= 1;
  }

  ushort (*Cb)[136] = (ushort (*)[136])SH;
  #pragma unroll
  for (int mi = 0; mi < 4; mi++) {
    __syncthreads();
    #pragma unroll
    for (int ni = 0; ni < 4; ni++)
      #pragma unroll
      for (int rr = 0; rr < 4; rr++) {
        float val = acc[mi][ni][rr];
        if (wsel == 2) val = 1.0f / (1.0f + __expf(-val));
        Cb[wm * 16 + (lane >> 4) * 4 + rr][wn * 64 + ni * 16 + (lane & 15)] = f2b(val);
      }
    __syncthreads();
    int rowL = t >> 3;
    int m = m0 + (rowL >> 4) * 64 + mi * 16 + (rowL & 15);
    int o0 = n0 + (t & 7) * 16;
    int b = m >> 11, s = m & 2047;
    int h = o0 >> 6, d = o0 & 63;
    ushort* dst = out + (((size_t)(b * H_ + h)) * S_ + s) * DH + d;
    uint4 v0 = *(uint4*)&Cb[rowL][(t & 7) * 16];
    uint4 v1 = *(uint4*)&Cb[rowL][(t & 7) * 16 + 8];
    *(uint4*)dst = v0;
    *(uint4*)(dst + 8) = v1;
  }
}

// ---------------- K2: dpfp + num + gate; gated written in-place over V ---------
// grid (4, 128), 256 threads. Wm B-frags in VGPRs; 3 barriers per 32-row chunk.
__global__ __launch_bounds__(256) void k_gate(
    const ushort* __restrict__ Kb, ushort* __restrict__ Vb,
    const ushort* __restrict__ Bgb, const float* __restrict__ Wmem,
    const float* __restrict__ z) {
  __shared__ ushort mkL[32][392];
  __shared__ ushort kb[32][64];
  __shared__ ushort VL[32][64];
  __shared__ ushort BgL[32][64];
  __shared__ ushort gN[32][72];
  __shared__ float rden[32];
  const int t = threadIdx.x, l = t & 63, w = t >> 6;
  const int l15 = l & 15, lq = l >> 4;
  const int bh = blockIdx.y, sblk = blockIdx.x;
  const size_t rowbase = (size_t)bh * S_;

  float zr[6];
  #pragma unroll
  for (int i = 0; i < 6; i++) zr[i] = z[(size_t)bh * DK + l + 64 * i];

  // Wm B-fragments in registers: n = w*16+l15, k = k0i*32 + lq*8 + j
  const float* Wm = Wmem + (size_t)bh * (DK * DH);
  bf16x8 bw[12];
  #pragma unroll
  for (int k0i = 0; k0i < 12; k0i++) {
    bf16x8 tmp;
    #pragma unroll
    for (int j = 0; j < 8; j++)
      tmp[j] = (short)f2b(Wm[(size_t)(k0i * 32 + lq * 8 + j) * DH + w * 16 + l15]);
    bw[k0i] = tmp;
  }

  for (int ch = 0; ch < 16; ch++) {
    const int s0 = sblk * 512 + ch * 32;
    const size_t gb = (rowbase + s0) * DH + w * 512 + l * 8;
    __builtin_amdgcn_global_load_lds((const AS1 u32*)(Kb + gb),
        (AS3 u32*)(&kb[0][0] + w * 512), 16, 0, 0);
    __builtin_amdgcn_global_load_lds((const AS1 u32*)(Vb + gb),
        (AS3 u32*)(&VL[0][0] + w * 512), 16, 0, 0);
    __builtin_amdgcn_global_load_lds((const AS1 u32*)(Bgb + gb),
        (AS3 u32*)(&BgL[0][0] + w * 512), 16, 0, 0);
    __syncthreads();
    // DPFP: wave w handles rows w*8 .. w*8+7; lane l owns features f = l+64i
    #pragma unroll
    for (int rr = 0; rr < 8; rr++) {
      int r = w * 8 + rr;
      float k1 = b2f(kb[r][l]);
      float rp = fmaxf(k1, 0.f), rn = fmaxf(-k1, 0.f);
      float v[6];
      float ssq = 0.f;
      #pragma unroll
      for (int i = 0; i < 6; i++) {
        int f = l + 64 * i, jj = f >> 7, i2 = (f - jj - 1) & 127;
        float k2 = b2f(kb[r][i2 & 63]);
        float xb2 = (i2 >= 64) ? fmaxf(-k2, 0.f) : fmaxf(k2, 0.f);
        float xa = (i & 1) ? rn : rp;
        v[i] = xa * xb2;
        ssq += v[i] * v[i];
      }
      #pragma unroll
      for (int o = 1; o < 64; o <<= 1) ssq += __shfl_xor(ssq, o);
      float inv = 1.0f / fmaxf(sqrtf(ssq), 1e-12f);
      float ds = 0.f;
      #pragma unroll
      for (int i = 0; i < 6; i++) {
        float nv = v[i] * inv;
        mkL[r][l + 64 * i] = f2b(nv);
        ds += zr[i] * nv;
      }
      #pragma unroll
      for (int o = 1; o < 64; o <<= 1) ds += __shfl_xor(ds, o);
      if (l == 0) rden[r] = 1.0f / (ds + 1e-5f);
    }
    __syncthreads();
    // num GEMM: wave w owns n-quadrant w; mi = 0,1
    f32x4 an[2] = {};
    #pragma unroll
    for (int k0i = 0; k0i < 12; k0i++)
      #pragma unroll
      for (int mi = 0; mi < 2; mi++) {
        bf16x8 af = *(const bf16x8*)&mkL[mi * 16 + l15][k0i * 32 + lq * 8];
        an[mi] = __builtin_amdgcn_mfma_f32_16x16x32_bf16(af, bw[k0i], an[mi], 0, 0, 0);
      }
    // gate -> gN
    #pragma unroll
    for (int mi = 0; mi < 2; mi++)
      #pragma unroll
      for (int rr2 = 0; rr2 < 4; rr2++) {
        int crow = mi * 16 + lq * 4 + rr2;
        int d = w * 16 + l15;
        float vv = b2f(VL[crow][d]);
        float bg = b2f(BgL[crow][d]);
        gN[crow][d] = f2b((vv - an[mi][rr2] * rden[crow]) * bg);
      }
    __syncthreads();
    // coalesced in-place store of gated over V
    {
      int r = t >> 3, sg = t & 7;
      uint4 vv = *(const uint4*)&gN[r][sg * 8];
      *(uint4*)(Vb + (rowbase + s0 + r) * DH + sg * 8) = vv;
    }
  }
}

// ---------------- K3: dpfp (recompute) + assoc, bf16 split-K partials ----------
// grid (4, 128), 512 threads (8 waves x 48 feature-rows).
__global__ __launch_bounds__(512) void k_assoc2(
    const ushort* __restrict__ Kb, const ushort* __restrict__ gated,
    ushort* __restrict__ part) {
  __shared__ ushort mkL[32][388];
  __shared__ ushort kb[32][64];
  __shared__ ushort gNat[32][64];
  const int t = threadIdx.x, l = t & 63, w = t >> 6;
  const int l15 = l & 15, lq = l >> 4;
  const int bh = blockIdx.y, seg = blockIdx.x;
  const size_t rowbase = (size_t)bh * S_;
  f32x4 acc[3][4] = {};

  for (int ch = 0; ch < 16; ch++) {
    const int s0 = seg * 512 + ch * 32;
    if (w < 4) {
      __builtin_amdgcn_global_load_lds(
          (const AS1 u32*)(Kb + (rowbase + s0) * DH + w * 512 + l * 8),
          (AS3 u32*)(&kb[0][0] + w * 512), 16, 0, 0);
    } else {
      int w4 = w - 4;
      __builtin_amdgcn_global_load_lds(
          (const AS1 u32*)(gated + (rowbase + s0) * DH + w4 * 512 + l * 8),
          (AS3 u32*)(&gNat[0][0] + w4 * 512), 16, 0, 0);
    }
    __syncthreads();
    // DPFP: wave w handles rows w*4 .. w*4+3
    #pragma unroll
    for (int rr = 0; rr < 4; rr++) {
      int r = w * 4 + rr;
      float k1 = b2f(kb[r][l]);
      float rp = fmaxf(k1, 0.f), rn = fmaxf(-k1, 0.f);
      float v[6];
      float ssq = 0.f;
      #pragma unroll
      for (int i = 0; i < 6; i++) {
        int f = l + 64 * i, jj = f >> 7, i2 = (f - jj - 1) & 127;
        float k2 = b2f(kb[r][i2 & 63]);
        float xb2 = (i2 >= 64) ? fmaxf(-k2, 0.f) : fmaxf(k2, 0.f);
        float xa = (i & 1) ? rn : rp;
        v[i] = xa * xb2;
        ssq += v[i] * v[i];
      }
      #pragma unroll
      for (int o = 1; o < 64; o <<= 1) ssq += __shfl_xor(ssq, o);
      float inv = 1.0f / fmaxf(sqrtf(ssq), 1e-12f);
      #pragma unroll
      for (int i = 0; i < 6; i++) mkL[r][l + 64 * i] = f2b(v[i] * inv);
    }
    __syncthreads();
    // assoc: K = 32 (one k-step). B-frags from gNat, A-frags from mkL (gathers).
    bf16x8 bfr[4];
    #pragma unroll
    for (int n2 = 0; n2 < 4; n2++) {
      bf16x8 bb;
      #pragma unroll
      for (int j = 0; j < 8; j++) bb[j] = (short)gNat[lq * 8 + j][n2 * 16 + l15];
      bfr[n2] = bb;
    }
    #pragma unroll
    for (int m2 = 0; m2 < 3; m2++) {
      bf16x8 aa;
      #pragma unroll
      for (int j = 0; j < 8; j++)
        aa[j] = (short)mkL[lq * 8 + j][w * 48 + m2 * 16 + l15];
      #pragma unroll
      for (int n2 = 0; n2 < 4; n2++)
        acc[m2][n2] = __builtin_amdgcn_mfma_f32_16x16x32_bf16(aa, bfr[n2], acc[m2][n2], 0, 0, 0);
    }
    __syncthreads();
  }
  ushort* pb = part + ((size_t)bh * 4 + seg) * (DK * DH);
  #pragma unroll
  for (int m2 = 0; m2 < 3; m2++)
    #pragma unroll
    for (int n2 = 0; n2 < 4; n2++)
      #pragma unroll
      for (int rc = 0; rc < 4; rc++)
        pb[(size_t)(w * 48 + m2 * 16 + lq * 4 + rc) * DH + n2 * 16 + l15] =
            f2b(acc[m2][n2][rc]);
}

// ---------------- K4: out = Wmem + sum of 4 bf16 partials ----------------------
__global__ __launch_bounds__(256) void k_reduce(
    const float* __restrict__ Wmem, const ushort* __restrict__ part,
    float* __restrict__ out) {
  size_t i4 = (size_t)blockIdx.x * 256 + threadIdx.x;   // over 786432 float4s
  int bh = (int)(i4 / 6144);
  size_t r4 = i4 - (size_t)bh * 6144;
  float4 acc = *(const float4*)(Wmem + i4 * 4);
  #pragma unroll
  for (int k = 0; k < 4; k++) {
    const ushort* pp = part + ((size_t)bh * 4 + k) * (DK * DH) + r4 * 4;
    ushort4 pv = *(const ushort4*)pp;
    acc.x += b2f(pv.x);
    acc.y += b2f(pv.y);
    acc.z += b2f(pv.z);
    acc.w += b2f(pv.w);
  }
  *(float4*)(out + i4 * 4) = acc;
}

extern "C" void kernel_launch(void* const* d_in, const int* in_sizes, int n_in,
                              void* d_out, int out_size, void* d_ws, size_t ws_size,
                              hipStream_t stream) {
  const float* X  = (const float*)d_in[0];
  const float* Wk = (const float*)d_in[1];
  const float* Wv = (const float*)d_in[2];
  const float* Wb = (const float*)d_in[3];
  const float* Wm = (const float*)d_in[4];
  const float* z  = (const float*)d_in[5];
  float* out = (float*)d_out;
  char* ws = (char*)d_ws;

  // ws layout (~140.5 MB total; ws_size >= 170 MB proven):
  //   Xb    : 0          .. 33,554,432   (dead after k_proj; part bf16 aliases)
  //   Wball : 33,554,432 .. 39,845,888
  //   kvb   : 39,845,888 .. 140,509,184  (K | V->gated in-place | sig(B))
  ushort* Xb    = (ushort*)(ws);
  ushort* Wball = (ushort*)(ws + 33554432ull);
  ushort* kvb   = (ushort*)(ws + 39845888ull);
  ushort* part  = (ushort*)(ws);                  // 25.2 MB, aliases dead Xb
  ushort* Kb  = kvb;
  ushort* Vb  = kvb + (size_t)B_ * H_ * S_ * DH;  // V, then gated in-place
  ushort* Bgb = kvb + 2ull * (size_t)B_ * H_ * S_ * DH;

  k_cvt   <<<dim3(2048), 256, 0, stream>>>(X, Wk, Wv, Wb, Xb, Wball);
  k_proj  <<<dim3(128, 8, 3), 256, 0, stream>>>(Xb, Wball, kvb);
  k_gate  <<<dim3(4, B_ * H_), 256, 0, stream>>>(Kb, Vb, Bgb, Wm, z);
  k_assoc2<<<dim3(4, B_ * H_), 512, 0, stream>>>(Kb, Vb, part);
  k_reduce<<<dim3(3072), 256, 0, stream>>>(Wm, part, out);
}

// Round 10
// 311.940 us; speedup vs baseline: 1.0852x; 1.0852x over previous
//
#include <hip/hip_runtime.h>
#include <hip/hip_bf16.h>

#define B_ 8
#define S_ 2048
#define DM 1024
#define H_ 16
#define DH 64
#define DK 384

#define AS3 __attribute__((address_space(3)))
#define AS1 __attribute__((address_space(1)))
typedef unsigned int u32;

typedef __attribute__((ext_vector_type(8))) short bf16x8;
typedef __attribute__((ext_vector_type(4))) short bf16x4;
typedef __attribute__((ext_vector_type(4))) float f32x4;

static __device__ __forceinline__ ushort f2b(float f) {
  __hip_bfloat16 h = __float2bfloat16(f);
  return *reinterpret_cast<ushort*>(&h);
}
static __device__ __forceinline__ float b2f(ushort u) {
  __hip_bfloat16 h;
  *reinterpret_cast<ushort*>(&h) = u;
  return __bfloat162float(h);
}

// ---------------- K0: convert X and Wk/Wv/Wb to bf16 (once) --------------------
__global__ __launch_bounds__(256) void k_cvt(
    const float* __restrict__ X, const float* __restrict__ Wk,
    const float* __restrict__ Wv, const float* __restrict__ Wb,
    ushort* __restrict__ Xb, ushort* __restrict__ Wball) {
  const int total = 2097152 + 3 * 131072;
  int c = blockIdx.x * 256 + threadIdx.x;
  const int stride = gridDim.x * 256;
  for (; c < total; c += stride) {
    const float* s;
    ushort* d;
    size_t off;
    if (c < 2097152) { s = X; d = Xb; off = (size_t)c; }
    else {
      int cc = c - 2097152;
      int wsel = cc >> 17;
      off = (size_t)(cc & 131071);
      s = wsel == 0 ? Wk : (wsel == 1 ? Wv : Wb);
      d = Wball + (size_t)wsel * (DM * DM);
    }
    float4 a = *(const float4*)(s + off * 8);
    float4 b = *(const float4*)(s + off * 8 + 4);
    ushort u[8] = { f2b(a.x), f2b(a.y), f2b(a.z), f2b(a.w),
                    f2b(b.x), f2b(b.y), f2b(b.z), f2b(b.w) };
    *(uint4*)(d + off * 8) = *(uint4*)u;
  }
}

// ---------------- K1: projection GEMM  Y = Xb @ Wb^T, dbuf + XCD swizzle -------
__global__ __launch_bounds__(256) void k_proj(
    const ushort* __restrict__ Xb, const ushort* __restrict__ Wball,
    ushort* __restrict__ kvb) {
  __shared__ ushort SH[4 * 8192];              // As[2] | Bs[2]  (64 KB)
  ushort* As = SH;
  ushort* Bs = SH + 2 * 8192;
  const int t = threadIdx.x, lane = t & 63, w = t >> 6;
  const int wm = w >> 1, wn = w & 1;
  const int bid = blockIdx.x + (blockIdx.y << 7) + (blockIdx.z << 10);
  const int c = bid & 7, r = bid >> 3;
  const int xb = c * 16 + (r & 15);
  const int rest = r >> 4;
  const int yb = rest & 7, zb = rest >> 3;
  const int m0 = xb * 128;
  const int n0 = yb * 128;
  const int wsel = zb;
  const ushort* Wmat = Wball + (size_t)wsel * (DM * DM);
  ushort* out = kvb + (size_t)wsel * ((size_t)B_ * H_ * S_ * DH);

  const int rowst = (lane >> 3);
  const int colsw = ((lane & 7) ^ rowst) << 3;

  auto STAGE = [&](int buf, int k0) {
    #pragma unroll
    for (int j = 0; j < 4; j++) {
      int row = (w * 4 + j) * 8 + rowst;
      __builtin_amdgcn_global_load_lds(
          (const AS1 u32*)(Xb + (size_t)(m0 + row) * DM + k0 + colsw),
          (AS3 u32*)(As + buf * 8192 + (w * 4 + j) * 512), 16, 0, 0);
      __builtin_amdgcn_global_load_lds(
          (const AS1 u32*)(Wmat + (size_t)(n0 + row) * DM + k0 + colsw),
          (AS3 u32*)(Bs + buf * 8192 + (w * 4 + j) * 512), 16, 0, 0);
    }
  };

  f32x4 acc[4][4] = {};
  STAGE(0, 0);
  __syncthreads();
  int cur = 0;
  for (int kt = 0; kt < 16; kt++) {
    if (kt < 15) STAGE(cur ^ 1, (kt + 1) * 64);
    const ushort* Ab = As + cur * 8192;
    const ushort* Bb = Bs + cur * 8192;
    #pragma unroll
    for (int kk2 = 0; kk2 < 2; kk2++) {
      const int csw = (((lane >> 4) + 4 * kk2) ^ (lane & 7)) << 3;
      bf16x8 af[4], bfr[4];
      #pragma unroll
      for (int mi = 0; mi < 4; mi++)
        af[mi] = *(const bf16x8*)&Ab[(wm * 64 + mi * 16 + (lane & 15)) * 64 + csw];
      #pragma unroll
      for (int ni = 0; ni < 4; ni++)
        bfr[ni] = *(const bf16x8*)&Bb[(wn * 64 + ni * 16 + (lane & 15)) * 64 + csw];
      #pragma unroll
      for (int mi = 0; mi < 4; mi++)
        #pragma unroll
        for (int ni = 0; ni < 4; ni++)
          acc[mi][ni] = __builtin_amdgcn_mfma_f32_16x16x32_bf16(af[mi], bfr[ni], acc[mi][ni], 0, 0, 0);
    }
    __syncthreads();
    cur ^= 1;
  }

  ushort (*Cb)[136] = (ushort (*)[136])SH;
  #pragma unroll
  for (int mi = 0; mi < 4; mi++) {
    __syncthreads();
    #pragma unroll
    for (int ni = 0; ni < 4; ni++)
      #pragma unroll
      for (int rr = 0; rr < 4; rr++) {
        float val = acc[mi][ni][rr];
        if (wsel == 2) val = 1.0f / (1.0f + __expf(-val));
        Cb[wm * 16 + (lane >> 4) * 4 + rr][wn * 64 + ni * 16 + (lane & 15)] = f2b(val);
      }
    __syncthreads();
    int rowL = t >> 3;
    int m = m0 + (rowL >> 4) * 64 + mi * 16 + (rowL & 15);
    int o0 = n0 + (t & 7) * 16;
    int b = m >> 11, s = m & 2047;
    int h = o0 >> 6, d = o0 & 63;
    ushort* dst = out + (((size_t)(b * H_ + h)) * S_ + s) * DH + d;
    uint4 v0 = *(uint4*)&Cb[rowL][(t & 7) * 16];
    uint4 v1 = *(uint4*)&Cb[rowL][(t & 7) * 16 + 8];
    *(uint4*)dst = v0;
    *(uint4*)(dst + 8) = v1;
  }
}

// ---------------- K2: fused DPFP(reg) + num + gate + assoc ---------------------
// grid (4, 128), 512 threads (8 waves). Raw features stored; normalization
// folded: num scaled by inv at gate; inv folded into gLT for assoc.
__global__ __launch_bounds__(512) void k_fused3(
    const ushort* __restrict__ Kb, const ushort* __restrict__ Vb,
    const ushort* __restrict__ Bgb, const float* __restrict__ Wmem,
    const float* __restrict__ z, ushort* __restrict__ part) {
  __shared__ ushort kb[32][64];     // gload dests (linear)
  __shared__ ushort VL[32][64];
  __shared__ ushort BgL[32][64];
  __shared__ ushort mkL[32][392];   // raw mk, [s][feat]
  __shared__ ushort mkT[384][44];   // raw mk, [feat][s]
  __shared__ ushort gLT[64][44];    // inv-folded gated, [d][s]
  __shared__ float invL[32];
  __shared__ float rdenL[32];
  const int t = threadIdx.x, l = t & 63, w = t >> 6;
  const int l15 = l & 15, lq = l >> 4;
  const int bh = blockIdx.y, seg = blockIdx.x;
  const size_t rowbase = (size_t)bh * S_;
  const int mi = w >> 2, ni = w & 3;

  float zr[6];
  #pragma unroll
  for (int tt = 0; tt < 6; tt++) zr[tt] = z[(size_t)bh * DK + l + 64 * tt];

  // Wm B-frags in VGPRs: bw[k0i][j] = Wm[(k0i*32+lq*8+j)*64 + ni*16+l15]
  const float* Wm = Wmem + (size_t)bh * (DK * DH);
  bf16x8 bw[12];
  #pragma unroll
  for (int k0i = 0; k0i < 12; k0i++) {
    bf16x8 tmp;
    #pragma unroll
    for (int j = 0; j < 8; j++)
      tmp[j] = (short)f2b(Wm[(size_t)(k0i * 32 + lq * 8 + j) * DH + ni * 16 + l15]);
    bw[k0i] = tmp;
  }

  f32x4 acc[3][4] = {};

  auto STAGE = [&](int ch) {
    const int pw = w >> 1, sub = w & 1;
    if (pw < 3) {
      const ushort* src = pw == 0 ? Kb : (pw == 1 ? Vb : Bgb);
      ushort* dst = pw == 0 ? &kb[0][0] : (pw == 1 ? &VL[0][0] : &BgL[0][0]);
      const size_t gbase = (rowbase + seg * 512 + ch * 32) * DH;
      #pragma unroll
      for (int j = 0; j < 2; j++) {
        int q = sub * 2 + j;
        __builtin_amdgcn_global_load_lds(
            (const AS1 u32*)(src + gbase + q * 512 + l * 8),
            (AS3 u32*)(dst + q * 512), 16, 0, 0);
      }
    }
  };

  STAGE(0);
  __syncthreads();

  for (int ch = 0; ch < 16; ch++) {
    // ---- DPFP: wave-cooperative over rows w*4..w*4+3, features f = l + 64t --
    float xp[4], xn[4];
    #pragma unroll
    for (int r = 0; r < 4; r++) {
      float kv = b2f(kb[w * 4 + r][l]);
      xp[r] = fmaxf(kv, 0.f);
      xn[r] = fmaxf(-kv, 0.f);
    }
    float ssq[4] = {}, zs[4] = {};
    ushort4 mp[6];
    #pragma unroll
    for (int u = 0; u < 3; u++) {
      int ibe = (l - u - 1) & 127;
      int sl = ibe & 63, hb = ibe >> 6;
      #pragma unroll
      for (int r = 0; r < 4; r++) {
        float ps = __shfl(xp[r], sl), ns = __shfl(xn[r], sl);
        float xbe = hb ? ns : ps;     // partner for f = l + 128u   (xa = xp)
        float xbo = hb ? ps : ns;     // partner for f = l+64+128u  (xa = xn)
        float ve = xp[r] * xbe;
        float vo = xn[r] * xbo;
        ssq[r] += ve * ve + vo * vo;
        zs[r] += zr[2 * u] * ve + zr[2 * u + 1] * vo;
        ushort be = f2b(ve), bo = f2b(vo);
        mkL[w * 4 + r][l + 128 * u] = be;
        mkL[w * 4 + r][l + 128 * u + 64] = bo;
        ((ushort*)&mp[2 * u])[r] = be;
        ((ushort*)&mp[2 * u + 1])[r] = bo;
      }
    }
    #pragma unroll
    for (int tt = 0; tt < 6; tt++)
      *(ushort4*)&mkT[l + 64 * tt][w * 4] = mp[tt];
    #pragma unroll
    for (int r = 0; r < 4; r++) {
      #pragma unroll
      for (int o = 1; o < 64; o <<= 1) {
        ssq[r] += __shfl_xor(ssq[r], o);
        zs[r] += __shfl_xor(zs[r], o);
      }
    }
    if (l == 0) {
      #pragma unroll
      for (int r = 0; r < 4; r++) {
        float inv = 1.0f / fmaxf(sqrtf(ssq[r]), 1e-12f);
        invL[w * 4 + r] = inv;
        rdenL[w * 4 + r] = 1.0f / (inv * zs[r] + 1e-5f);
      }
    }
    __syncthreads();   // A: mkL/mkT/invL/rdenL ready

    // ---- num GEMM (raw) + gate -> gLT (inv-folded) ----
    f32x4 an = {};
    #pragma unroll
    for (int k0i = 0; k0i < 12; k0i++) {
      bf16x8 af = *(const bf16x8*)&mkL[mi * 16 + l15][k0i * 32 + lq * 8];
      an = __builtin_amdgcn_mfma_f32_16x16x32_bf16(af, bw[k0i], an, 0, 0, 0);
    }
    {
      ushort4 gp;
      int d = ni * 16 + l15;
      #pragma unroll
      for (int rr = 0; rr < 4; rr++) {
        int crow = mi * 16 + lq * 4 + rr;
        float invv = invL[crow];
        float prev = an[rr] * invv * rdenL[crow];
        float g = (b2f(VL[crow][d]) - prev) * b2f(BgL[crow][d]);
        ((ushort*)&gp)[rr] = f2b(g * invv);
      }
      *(ushort4*)&gLT[d][mi * 16 + lq * 4] = gp;
    }
    __syncthreads();   // B: gLT ready; kb/VL/BgL fully consumed

    if (ch < 15) STAGE(ch + 1);   // overlap HBM latency under assoc

    // ---- assoc: wave owns feature rows [w*48, w*48+48) ----
    {
      bf16x8 bfr[4];
      #pragma unroll
      for (int n2 = 0; n2 < 4; n2++) {
        bf16x4 blo = *(const bf16x4*)&gLT[n2 * 16 + l15][lq * 8];
        bf16x4 bhi = *(const bf16x4*)&gLT[n2 * 16 + l15][lq * 8 + 4];
        bfr[n2] = __builtin_shufflevector(blo, bhi, 0, 1, 2, 3, 4, 5, 6, 7);
      }
      #pragma unroll
      for (int m2 = 0; m2 < 3; m2++) {
        bf16x4 alo = *(const bf16x4*)&mkT[w * 48 + m2 * 16 + l15][lq * 8];
        bf16x4 ahi = *(const bf16x4*)&mkT[w * 48 + m2 * 16 + l15][lq * 8 + 4];
        bf16x8 af = __builtin_shufflevector(alo, ahi, 0, 1, 2, 3, 4, 5, 6, 7);
        #pragma unroll
        for (int n2 = 0; n2 < 4; n2++)
          acc[m2][n2] = __builtin_amdgcn_mfma_f32_16x16x32_bf16(af, bfr[n2], acc[m2][n2], 0, 0, 0);
      }
    }
    __syncthreads();   // C: assoc reads done; staged loads drained
  }

  ushort* pb = part + ((size_t)bh * 4 + seg) * (DK * DH);
  #pragma unroll
  for (int m2 = 0; m2 < 3; m2++)
    #pragma unroll
    for (int n2 = 0; n2 < 4; n2++)
      #pragma unroll
      for (int rc = 0; rc < 4; rc++)
        pb[(size_t)(w * 48 + m2 * 16 + lq * 4 + rc) * DH + n2 * 16 + l15] =
            f2b(acc[m2][n2][rc]);
}

// ---------------- K3: out = Wmem + sum of 4 bf16 partials ----------------------
__global__ __launch_bounds__(256) void k_reduce(
    const float* __restrict__ Wmem, const ushort* __restrict__ part,
    float* __restrict__ out) {
  size_t i4 = (size_t)blockIdx.x * 256 + threadIdx.x;   // over 786432 float4s
  int bh = (int)(i4 / 6144);
  size_t r4 = i4 - (size_t)bh * 6144;
  float4 acc = *(const float4*)(Wmem + i4 * 4);
  #pragma unroll
  for (int k = 0; k < 4; k++) {
    const ushort* pp = part + ((size_t)bh * 4 + k) * (DK * DH) + r4 * 4;
    ushort4 pv = *(const ushort4*)pp;
    acc.x += b2f(pv.x);
    acc.y += b2f(pv.y);
    acc.z += b2f(pv.z);
    acc.w += b2f(pv.w);
  }
  *(float4*)(out + i4 * 4) = acc;
}

extern "C" void kernel_launch(void* const* d_in, const int* in_sizes, int n_in,
                              void* d_out, int out_size, void* d_ws, size_t ws_size,
                              hipStream_t stream) {
  const float* X  = (const float*)d_in[0];
  const float* Wk = (const float*)d_in[1];
  const float* Wv = (const float*)d_in[2];
  const float* Wb = (const float*)d_in[3];
  const float* Wm = (const float*)d_in[4];
  const float* z  = (const float*)d_in[5];
  float* out = (float*)d_out;
  char* ws = (char*)d_ws;

  // ws layout (~140.5 MB; ws_size >= 170 MB proven):
  //   Xb    : 0          .. 33,554,432   (dead after k_proj; part aliases)
  //   Wball : 33,554,432 .. 39,845,888
  //   kvb   : 39,845,888 .. 140,509,184  (K | V | sig(B))
  ushort* Xb    = (ushort*)(ws);
  ushort* Wball = (ushort*)(ws + 33554432ull);
  ushort* kvb   = (ushort*)(ws + 39845888ull);
  ushort* part  = (ushort*)(ws);                  // 25.2 MB, aliases dead Xb
  ushort* Kb  = kvb;
  ushort* Vb  = kvb + (size_t)B_ * H_ * S_ * DH;
  ushort* Bgb = kvb + 2ull * (size_t)B_ * H_ * S_ * DH;

  k_cvt   <<<dim3(2048), 256, 0, stream>>>(X, Wk, Wv, Wb, Xb, Wball);
  k_proj  <<<dim3(128, 8, 3), 256, 0, stream>>>(Xb, Wball, kvb);
  k_fused3<<<dim3(4, B_ * H_), 512, 0, stream>>>(Kb, Vb, Bgb, Wm, z, part);
  k_reduce<<<dim3(3072), 256, 0, stream>>>(Wm, part, out);
}

// Round 11
// 289.057 us; speedup vs baseline: 1.1711x; 1.0792x over previous
//
#include <hip/hip_runtime.h>
#include <hip/hip_bf16.h>

#define B_ 8
#define S_ 2048
#define DM 1024
#define H_ 16
#define DH 64
#define DK 384

#define AS3 __attribute__((address_space(3)))
#define AS1 __attribute__((address_space(1)))
typedef unsigned int u32;

typedef __attribute__((ext_vector_type(8))) short bf16x8;
typedef __attribute__((ext_vector_type(4))) short bf16x4;
typedef __attribute__((ext_vector_type(4))) float f32x4;

static __device__ __forceinline__ ushort f2b(float f) {
  __hip_bfloat16 h = __float2bfloat16(f);
  return *reinterpret_cast<ushort*>(&h);
}
static __device__ __forceinline__ float b2f(ushort u) {
  __hip_bfloat16 h;
  *reinterpret_cast<ushort*>(&h) = u;
  return __bfloat162float(h);
}

// ---------------- K0: convert X and Wk/Wv/Wb to bf16 (once) --------------------
__global__ __launch_bounds__(256) void k_cvt(
    const float* __restrict__ X, const float* __restrict__ Wk,
    const float* __restrict__ Wv, const float* __restrict__ Wb,
    ushort* __restrict__ Xb, ushort* __restrict__ Wball) {
  const int total = 2097152 + 3 * 131072;
  int c = blockIdx.x * 256 + threadIdx.x;
  const int stride = gridDim.x * 256;
  for (; c < total; c += stride) {
    const float* s;
    ushort* d;
    size_t off;
    if (c < 2097152) { s = X; d = Xb; off = (size_t)c; }
    else {
      int cc = c - 2097152;
      int wsel = cc >> 17;
      off = (size_t)(cc & 131071);
      s = wsel == 0 ? Wk : (wsel == 1 ? Wv : Wb);
      d = Wball + (size_t)wsel * (DM * DM);
    }
    float4 a = *(const float4*)(s + off * 8);
    float4 b = *(const float4*)(s + off * 8 + 4);
    ushort u[8] = { f2b(a.x), f2b(a.y), f2b(a.z), f2b(a.w),
                    f2b(b.x), f2b(b.y), f2b(b.z), f2b(b.w) };
    *(uint4*)(d + off * 8) = *(uint4*)u;
  }
}

// ---------------- K1: projection GEMM  Y = Xb @ Wb^T, dbuf + XCD swizzle -------
__global__ __launch_bounds__(256) void k_proj(
    const ushort* __restrict__ Xb, const ushort* __restrict__ Wball,
    ushort* __restrict__ kvb) {
  __shared__ ushort SH[4 * 8192];              // As[2] | Bs[2]  (64 KB)
  ushort* As = SH;
  ushort* Bs = SH + 2 * 8192;
  const int t = threadIdx.x, lane = t & 63, w = t >> 6;
  const int wm = w >> 1, wn = w & 1;
  const int bid = blockIdx.x + (blockIdx.y << 7) + (blockIdx.z << 10);
  const int c = bid & 7, r = bid >> 3;
  const int xb = c * 16 + (r & 15);
  const int rest = r >> 4;
  const int yb = rest & 7, zb = rest >> 3;
  const int m0 = xb * 128;
  const int n0 = yb * 128;
  const int wsel = zb;
  const ushort* Wmat = Wball + (size_t)wsel * (DM * DM);
  ushort* out = kvb + (size_t)wsel * ((size_t)B_ * H_ * S_ * DH);

  const int rowst = (lane >> 3);
  const int colsw = ((lane & 7) ^ rowst) << 3;

  auto STAGE = [&](int buf, int k0) {
    #pragma unroll
    for (int j = 0; j < 4; j++) {
      int row = (w * 4 + j) * 8 + rowst;
      __builtin_amdgcn_global_load_lds(
          (const AS1 u32*)(Xb + (size_t)(m0 + row) * DM + k0 + colsw),
          (AS3 u32*)(As + buf * 8192 + (w * 4 + j) * 512), 16, 0, 0);
      __builtin_amdgcn_global_load_lds(
          (const AS1 u32*)(Wmat + (size_t)(n0 + row) * DM + k0 + colsw),
          (AS3 u32*)(Bs + buf * 8192 + (w * 4 + j) * 512), 16, 0, 0);
    }
  };

  f32x4 acc[4][4] = {};
  STAGE(0, 0);
  __syncthreads();
  int cur = 0;
  for (int kt = 0; kt < 16; kt++) {
    if (kt < 15) STAGE(cur ^ 1, (kt + 1) * 64);
    const ushort* Ab = As + cur * 8192;
    const ushort* Bb = Bs + cur * 8192;
    #pragma unroll
    for (int kk2 = 0; kk2 < 2; kk2++) {
      const int csw = (((lane >> 4) + 4 * kk2) ^ (lane & 7)) << 3;
      bf16x8 af[4], bfr[4];
      #pragma unroll
      for (int mi = 0; mi < 4; mi++)
        af[mi] = *(const bf16x8*)&Ab[(wm * 64 + mi * 16 + (lane & 15)) * 64 + csw];
      #pragma unroll
      for (int ni = 0; ni < 4; ni++)
        bfr[ni] = *(const bf16x8*)&Bb[(wn * 64 + ni * 16 + (lane & 15)) * 64 + csw];
      #pragma unroll
      for (int mi = 0; mi < 4; mi++)
        #pragma unroll
        for (int ni = 0; ni < 4; ni++)
          acc[mi][ni] = __builtin_amdgcn_mfma_f32_16x16x32_bf16(af[mi], bfr[ni], acc[mi][ni], 0, 0, 0);
    }
    __syncthreads();
    cur ^= 1;
  }

  ushort (*Cb)[136] = (ushort (*)[136])SH;
  #pragma unroll
  for (int mi = 0; mi < 4; mi++) {
    __syncthreads();
    #pragma unroll
    for (int ni = 0; ni < 4; ni++)
      #pragma unroll
      for (int rr = 0; rr < 4; rr++) {
        float val = acc[mi][ni][rr];
        if (wsel == 2) val = 1.0f / (1.0f + __expf(-val));
        Cb[wm * 16 + (lane >> 4) * 4 + rr][wn * 64 + ni * 16 + (lane & 15)] = f2b(val);
      }
    __syncthreads();
    int rowL = t >> 3;
    int m = m0 + (rowL >> 4) * 64 + mi * 16 + (rowL & 15);
    int o0 = n0 + (t & 7) * 16;
    int b = m >> 11, s = m & 2047;
    int h = o0 >> 6, d = o0 & 63;
    ushort* dst = out + (((size_t)(b * H_ + h)) * S_ + s) * DH + d;
    uint4 v0 = *(uint4*)&Cb[rowL][(t & 7) * 16];
    uint4 v1 = *(uint4*)&Cb[rowL][(t & 7) * 16 + 8];
    *(uint4*)dst = v0;
    *(uint4*)(dst + 8) = v1;
  }
}

// ---------------- K2: fused DPFP + num + gate + assoc (Gram-MFMA stats) --------
// grid (4, 128), 512 threads. mkL k-columns PERMUTED (pair-interleaved); the
// same permutation is applied to the Wm/z fragment gathers. mkT/part use true
// feature indices. ssq/zs via MFMA (Gram diag / z-masked column 0).
__global__ __launch_bounds__(512) void k_fused4(
    const ushort* __restrict__ Kb, const ushort* __restrict__ Vb,
    const ushort* __restrict__ Bgb, const float* __restrict__ Wmem,
    const float* __restrict__ z, ushort* __restrict__ part) {
  __shared__ ushort kb[32][64];     // gload dests (linear)
  __shared__ ushort VL[32][64];
  __shared__ ushort BgL[32][64];
  __shared__ u32 mkLd[32][196];     // raw mk, [s][perm-k pairs] (pitch 392 ush)
  __shared__ ushort mkT[384][36];   // raw mk, [true feat][s]
  __shared__ ushort gLT[64][36];    // inv-folded gated, [d][s]
  __shared__ ushort zL[384];        // permuted z (bf16)
  __shared__ float ssqL[32];
  __shared__ float zsL[32];
  const int t = threadIdx.x, l = t & 63, w = t >> 6;
  const int l15 = l & 15, lq = l >> 4;
  const int bh = blockIdx.y, seg = blockIdx.x;
  const size_t rowbase = (size_t)bh * S_;
  const int mi = w >> 2, ni = w & 3;

  // z (permuted) -> LDS
  for (int cc = t; cc < DK; cc += 512) {
    int u = cc >> 7, p = (cc & 127) >> 1, par = cc & 1;
    zL[cc] = f2b(z[(size_t)bh * DK + u * 128 + par * 64 + p]);
  }

  // Wm B-frags in VGPRs (permuted k): bw[k0i][j] = Wm[trueF(k0i*32+lq*8+j)][ni*16+l15]
  const float* Wm = Wmem + (size_t)bh * (DK * DH);
  bf16x8 bw[12];
  #pragma unroll
  for (int k0i = 0; k0i < 12; k0i++) {
    bf16x8 tmp;
    #pragma unroll
    for (int j = 0; j < 8; j++) {
      int cc = k0i * 32 + lq * 8 + j;
      int u = cc >> 7, p = (cc & 127) >> 1, par = cc & 1;
      tmp[j] = (short)f2b(Wm[(size_t)(u * 128 + par * 64 + p) * DH + ni * 16 + l15]);
    }
    bw[k0i] = tmp;
  }

  f32x4 acc[3][4] = {};

  auto STAGE = [&](int ch) {
    const int pw = w >> 1, sub = w & 1;
    if (pw < 3) {
      const ushort* src = pw == 0 ? Kb : (pw == 1 ? Vb : Bgb);
      ushort* dst = pw == 0 ? &kb[0][0] : (pw == 1 ? &VL[0][0] : &BgL[0][0]);
      const size_t gbase = (rowbase + seg * 512 + ch * 32) * DH;
      #pragma unroll
      for (int j = 0; j < 2; j++) {
        int q = sub * 2 + j;
        __builtin_amdgcn_global_load_lds(
            (const AS1 u32*)(src + gbase + q * 512 + l * 8),
            (AS3 u32*)(dst + q * 512), 16, 0, 0);
      }
    }
  };

  STAGE(0);
  __syncthreads();

  for (int ch = 0; ch < 16; ch++) {
    // ---- phase 1: DPFP features (packed shuffles), no reductions ----
    float xpv[4], xnv[4];
    u32 pks[4];
    #pragma unroll
    for (int r = 0; r < 4; r++) {
      float kv = b2f(kb[w * 4 + r][l]);
      xpv[r] = fmaxf(kv, 0.f);
      xnv[r] = fmaxf(-kv, 0.f);
      pks[r] = (u32)f2b(xpv[r]) | ((u32)f2b(xnv[r]) << 16);
    }
    ushort4 mp[6];
    #pragma unroll
    for (int u = 0; u < 3; u++) {
      int ie = (l - u - 1) & 127;
      int sl = ie & 63;
      bool sw = ie >= 64;
      #pragma unroll
      for (int r = 0; r < 4; r++) {
        u32 pp = (u32)__shfl((int)pks[r], sl);
        float ps = b2f((ushort)(pp & 0xffff));
        float ns = b2f((ushort)(pp >> 16));
        float xbe = sw ? ns : ps;
        float xbo = sw ? ps : ns;
        ushort bve = f2b(xpv[r] * xbe);
        ushort bvo = f2b(xnv[r] * xbo);
        mkLd[w * 4 + r][u * 64 + l] = (u32)bve | ((u32)bvo << 16);
        ((ushort*)&mp[2 * u])[r] = bve;
        ((ushort*)&mp[2 * u + 1])[r] = bvo;
      }
    }
    #pragma unroll
    for (int tt = 0; tt < 6; tt++)
      *(ushort4*)&mkT[l + 64 * tt][w * 4] = mp[tt];
    __syncthreads();   // A: mkLd/mkT ready

    // ---- phase 2: num GEMM + Gram(ssq) + z(zs) on the MFMA pipe ----
    const ushort* mkrow = (const ushort*)&mkLd[mi * 16 + l15][0];
    f32x4 an0 = {}, an1 = {}, gacc = {}, zacc = {};
    #pragma unroll
    for (int k0i = 0; k0i < 12; k0i += 2) {
      bf16x8 afA = *(const bf16x8*)(mkrow + k0i * 32 + lq * 8);
      bf16x8 afB = *(const bf16x8*)(mkrow + (k0i + 1) * 32 + lq * 8);
      an0 = __builtin_amdgcn_mfma_f32_16x16x32_bf16(afA, bw[k0i], an0, 0, 0, 0);
      an1 = __builtin_amdgcn_mfma_f32_16x16x32_bf16(afB, bw[k0i + 1], an1, 0, 0, 0);
      if (ni == 0) {
        gacc = __builtin_amdgcn_mfma_f32_16x16x32_bf16(afA, afA, gacc, 0, 0, 0);
        gacc = __builtin_amdgcn_mfma_f32_16x16x32_bf16(afB, afB, gacc, 0, 0, 0);
      }
      if (ni == 1) {
        bf16x8 zfA = *(const bf16x8*)&zL[k0i * 32 + lq * 8];
        bf16x8 zfB = *(const bf16x8*)&zL[(k0i + 1) * 32 + lq * 8];
        if (l15 != 0) {
          zfA = bf16x8{0, 0, 0, 0, 0, 0, 0, 0};
          zfB = bf16x8{0, 0, 0, 0, 0, 0, 0, 0};
        }
        zacc = __builtin_amdgcn_mfma_f32_16x16x32_bf16(afA, zfA, zacc, 0, 0, 0);
        zacc = __builtin_amdgcn_mfma_f32_16x16x32_bf16(afB, zfB, zacc, 0, 0, 0);
      }
    }
    f32x4 an = an0 + an1;
    if (ni == 0) {      // Gram diag -> ssqL (C[r][c]: r=lq*4+rc, c=l15)
      #pragma unroll
      for (int rc = 0; rc < 4; rc++)
        if (lq == (l15 >> 2) && (l15 & 3) == rc) ssqL[mi * 16 + l15] = gacc[rc];
    }
    if (ni == 1) {      // z column 0 -> zsL
      #pragma unroll
      for (int rc = 0; rc < 4; rc++)
        if (l15 == 0) zsL[mi * 16 + lq * 4 + rc] = zacc[rc];
    }
    __syncthreads();   // B1: ssqL/zsL ready

    // ---- gate -> gLT (inv-folded) ----
    {
      ushort4 gp;
      int d = ni * 16 + l15;
      #pragma unroll
      for (int rr = 0; rr < 4; rr++) {
        int crow = mi * 16 + lq * 4 + rr;
        float inv = 1.0f / fmaxf(sqrtf(ssqL[crow]), 1e-12f);
        float rden = 1.0f / (inv * zsL[crow] + 1e-5f);
        float prev = an[rr] * inv * rden;
        float g = (b2f(VL[crow][d]) - prev) * b2f(BgL[crow][d]);
        ((ushort*)&gp)[rr] = f2b(g * inv);
      }
      *(ushort4*)&gLT[d][mi * 16 + lq * 4] = gp;
    }
    __syncthreads();   // B2: gLT ready; kb/VL/BgL fully consumed

    if (ch < 15) STAGE(ch + 1);   // overlap HBM latency under assoc

    // ---- assoc: wave owns true-feature rows [w*48, w*48+48) ----
    {
      bf16x8 bfr[4];
      #pragma unroll
      for (int n2 = 0; n2 < 4; n2++) {
        bf16x4 blo = *(const bf16x4*)&gLT[n2 * 16 + l15][lq * 8];
        bf16x4 bhi = *(const bf16x4*)&gLT[n2 * 16 + l15][lq * 8 + 4];
        bfr[n2] = __builtin_shufflevector(blo, bhi, 0, 1, 2, 3, 4, 5, 6, 7);
      }
      #pragma unroll
      for (int m2 = 0; m2 < 3; m2++) {
        bf16x4 alo = *(const bf16x4*)&mkT[w * 48 + m2 * 16 + l15][lq * 8];
        bf16x4 ahi = *(const bf16x4*)&mkT[w * 48 + m2 * 16 + l15][lq * 8 + 4];
        bf16x8 af = __builtin_shufflevector(alo, ahi, 0, 1, 2, 3, 4, 5, 6, 7);
        #pragma unroll
        for (int n2 = 0; n2 < 4; n2++)
          acc[m2][n2] = __builtin_amdgcn_mfma_f32_16x16x32_bf16(af, bfr[n2], acc[m2][n2], 0, 0, 0);
      }
    }
    __syncthreads();   // C: assoc reads done; staged loads drained
  }

  ushort* pb = part + ((size_t)bh * 4 + seg) * (DK * DH);
  #pragma unroll
  for (int m2 = 0; m2 < 3; m2++)
    #pragma unroll
    for (int n2 = 0; n2 < 4; n2++)
      #pragma unroll
      for (int rc = 0; rc < 4; rc++)
        pb[(size_t)(w * 48 + m2 * 16 + lq * 4 + rc) * DH + n2 * 16 + l15] =
            f2b(acc[m2][n2][rc]);
}

// ---------------- K3: out = Wmem + sum of 4 bf16 partials ----------------------
__global__ __launch_bounds__(256) void k_reduce(
    const float* __restrict__ Wmem, const ushort* __restrict__ part,
    float* __restrict__ out) {
  size_t i4 = (size_t)blockIdx.x * 256 + threadIdx.x;   // over 786432 float4s
  int bh = (int)(i4 / 6144);
  size_t r4 = i4 - (size_t)bh * 6144;
  float4 acc = *(const float4*)(Wmem + i4 * 4);
  #pragma unroll
  for (int k = 0; k < 4; k++) {
    const ushort* pp = part + ((size_t)bh * 4 + k) * (DK * DH) + r4 * 4;
    ushort4 pv = *(const ushort4*)pp;
    acc.x += b2f(pv.x);
    acc.y += b2f(pv.y);
    acc.z += b2f(pv.z);
    acc.w += b2f(pv.w);
  }
  *(float4*)(out + i4 * 4) = acc;
}

extern "C" void kernel_launch(void* const* d_in, const int* in_sizes, int n_in,
                              void* d_out, int out_size, void* d_ws, size_t ws_size,
                              hipStream_t stream) {
  const float* X  = (const float*)d_in[0];
  const float* Wk = (const float*)d_in[1];
  const float* Wv = (const float*)d_in[2];
  const float* Wb = (const float*)d_in[3];
  const float* Wm = (const float*)d_in[4];
  const float* z  = (const float*)d_in[5];
  float* out = (float*)d_out;
  char* ws = (char*)d_ws;

  // ws layout (~140.5 MB; ws_size >= 170 MB proven):
  //   Xb    : 0          .. 33,554,432   (dead after k_proj; part aliases)
  //   Wball : 33,554,432 .. 39,845,888
  //   kvb   : 39,845,888 .. 140,509,184  (K | V | sig(B))
  ushort* Xb    = (ushort*)(ws);
  ushort* Wball = (ushort*)(ws + 33554432ull);
  ushort* kvb   = (ushort*)(ws + 39845888ull);
  ushort* part  = (ushort*)(ws);                  // 25.2 MB, aliases dead Xb
  ushort* Kb  = kvb;
  ushort* Vb  = kvb + (size_t)B_ * H_ * S_ * DH;
  ushort* Bgb = kvb + 2ull * (size_t)B_ * H_ * S_ * DH;

  k_cvt   <<<dim3(2048), 256, 0, stream>>>(X, Wk, Wv, Wb, Xb, Wball);
  k_proj  <<<dim3(128, 8, 3), 256, 0, stream>>>(Xb, Wball, kvb);
  k_fused4<<<dim3(4, B_ * H_), 512, 0, stream>>>(Kb, Vb, Bgb, Wm, z, part);
  k_reduce<<<dim3(3072), 256, 0, stream>>>(Wm, part, out);
}

// Round 12
// 281.933 us; speedup vs baseline: 1.2007x; 1.0253x over previous
//
#include <hip/hip_runtime.h>
#include <hip/hip_bf16.h>

#define B_ 8
#define S_ 2048
#define DM 1024
#define H_ 16
#define DH 64
#define DK 384

#define AS3 __attribute__((address_space(3)))
#define AS1 __attribute__((address_space(1)))
typedef unsigned int u32;

typedef __attribute__((ext_vector_type(8))) short bf16x8;
typedef __attribute__((ext_vector_type(4))) short bf16x4;
typedef __attribute__((ext_vector_type(4))) float f32x4;

static __device__ __forceinline__ ushort f2b(float f) {
  __hip_bfloat16 h = __float2bfloat16(f);
  return *reinterpret_cast<ushort*>(&h);
}
static __device__ __forceinline__ float b2f(ushort u) {
  __hip_bfloat16 h;
  *reinterpret_cast<ushort*>(&h) = u;
  return __bfloat162float(h);
}

// ---------------- K0: convert X and Wk/Wv/Wb to bf16 (once) --------------------
__global__ __launch_bounds__(256) void k_cvt(
    const float* __restrict__ X, const float* __restrict__ Wk,
    const float* __restrict__ Wv, const float* __restrict__ Wb,
    ushort* __restrict__ Xb, ushort* __restrict__ Wball) {
  const int total = 2097152 + 3 * 131072;
  int c = blockIdx.x * 256 + threadIdx.x;
  const int stride = gridDim.x * 256;
  for (; c < total; c += stride) {
    const float* s;
    ushort* d;
    size_t off;
    if (c < 2097152) { s = X; d = Xb; off = (size_t)c; }
    else {
      int cc = c - 2097152;
      int wsel = cc >> 17;
      off = (size_t)(cc & 131071);
      s = wsel == 0 ? Wk : (wsel == 1 ? Wv : Wb);
      d = Wball + (size_t)wsel * (DM * DM);
    }
    float4 a = *(const float4*)(s + off * 8);
    float4 b = *(const float4*)(s + off * 8 + 4);
    ushort u[8] = { f2b(a.x), f2b(a.y), f2b(a.z), f2b(a.w),
                    f2b(b.x), f2b(b.y), f2b(b.z), f2b(b.w) };
    *(uint4*)(d + off * 8) = *(uint4*)u;
  }
}

// ---------------- K1: projection GEMM  Y = Xb @ Wb^T, dbuf + XCD swizzle -------
__global__ __launch_bounds__(256) void k_proj(
    const ushort* __restrict__ Xb, const ushort* __restrict__ Wball,
    ushort* __restrict__ kvb) {
  __shared__ ushort SH[4 * 8192];              // As[2] | Bs[2]  (64 KB)
  ushort* As = SH;
  ushort* Bs = SH + 2 * 8192;
  const int t = threadIdx.x, lane = t & 63, w = t >> 6;
  const int wm = w >> 1, wn = w & 1;
  const int bid = blockIdx.x + (blockIdx.y << 7) + (blockIdx.z << 10);
  const int c = bid & 7, r = bid >> 3;
  const int xb = c * 16 + (r & 15);
  const int rest = r >> 4;
  const int yb = rest & 7, zb = rest >> 3;
  const int m0 = xb * 128;
  const int n0 = yb * 128;
  const int wsel = zb;
  const ushort* Wmat = Wball + (size_t)wsel * (DM * DM);
  ushort* out = kvb + (size_t)wsel * ((size_t)B_ * H_ * S_ * DH);

  const int rowst = (lane >> 3);
  const int colsw = ((lane & 7) ^ rowst) << 3;

  auto STAGE = [&](int buf, int k0) {
    #pragma unroll
    for (int j = 0; j < 4; j++) {
      int row = (w * 4 + j) * 8 + rowst;
      __builtin_amdgcn_global_load_lds(
          (const AS1 u32*)(Xb + (size_t)(m0 + row) * DM + k0 + colsw),
          (AS3 u32*)(As + buf * 8192 + (w * 4 + j) * 512), 16, 0, 0);
      __builtin_amdgcn_global_load_lds(
          (const AS1 u32*)(Wmat + (size_t)(n0 + row) * DM + k0 + colsw),
          (AS3 u32*)(Bs + buf * 8192 + (w * 4 + j) * 512), 16, 0, 0);
    }
  };

  f32x4 acc[4][4] = {};
  STAGE(0, 0);
  __syncthreads();
  int cur = 0;
  for (int kt = 0; kt < 16; kt++) {
    if (kt < 15) STAGE(cur ^ 1, (kt + 1) * 64);
    const ushort* Ab = As + cur * 8192;
    const ushort* Bb = Bs + cur * 8192;
    #pragma unroll
    for (int kk2 = 0; kk2 < 2; kk2++) {
      const int csw = (((lane >> 4) + 4 * kk2) ^ (lane & 7)) << 3;
      bf16x8 af[4], bfr[4];
      #pragma unroll
      for (int mi = 0; mi < 4; mi++)
        af[mi] = *(const bf16x8*)&Ab[(wm * 64 + mi * 16 + (lane & 15)) * 64 + csw];
      #pragma unroll
      for (int ni = 0; ni < 4; ni++)
        bfr[ni] = *(const bf16x8*)&Bb[(wn * 64 + ni * 16 + (lane & 15)) * 64 + csw];
      #pragma unroll
      for (int mi = 0; mi < 4; mi++)
        #pragma unroll
        for (int ni = 0; ni < 4; ni++)
          acc[mi][ni] = __builtin_amdgcn_mfma_f32_16x16x32_bf16(af[mi], bfr[ni], acc[mi][ni], 0, 0, 0);
    }
    __syncthreads();
    cur ^= 1;
  }

  // Epilogue: single 128x136 LDS bounce (2 barriers total), coalesced stores.
  ushort (*Cb)[136] = (ushort (*)[136])SH;   // 34.8 KB, aliases As/Bs
  #pragma unroll
  for (int mi = 0; mi < 4; mi++)
    #pragma unroll
    for (int ni = 0; ni < 4; ni++)
      #pragma unroll
      for (int rr = 0; rr < 4; rr++) {
        float val = acc[mi][ni][rr];
        if (wsel == 2) val = 1.0f / (1.0f + __expf(-val));
        Cb[wm * 64 + mi * 16 + (lane >> 4) * 4 + rr]
          [wn * 64 + ni * 16 + (lane & 15)] = f2b(val);
      }
  __syncthreads();
  #pragma unroll
  for (int q = 0; q < 8; q++) {
    int idx = q * 256 + t;          // 0..2047
    int lm = idx >> 4;              // local row 0..127
    int c16 = idx & 15;             // 16B chunk of the 256B row
    int m = m0 + lm;
    int b = m >> 11, s = m & 2047;
    int o0 = n0 + c16 * 8;
    int h = o0 >> 6, d = o0 & 63;
    *(uint4*)(out + (((size_t)(b * H_ + h)) * S_ + s) * DH + d) =
        *(uint4*)&Cb[lm][c16 * 8];
  }
}

// ---------------- K2: fused DPFP + num + gate + assoc (wave-local stats) -------
// grid (4, 128), 512 threads. 3 barriers/chunk. ssq/zs per-wave via Gram/z MFMA
// (Gram diag broadcast by one __shfl; zacc is column-independent -> in-lane).
__global__ __launch_bounds__(512) void k_fused5(
    const ushort* __restrict__ Kb, const ushort* __restrict__ Vb,
    const ushort* __restrict__ Bgb, const float* __restrict__ Wmem,
    const float* __restrict__ z, ushort* __restrict__ part) {
  __shared__ ushort kb[32][64];     // gload dests (linear)
  __shared__ ushort VL[32][64];
  __shared__ ushort BgL[32][64];
  __shared__ u32 mkLd[32][196];     // raw mk, [s][perm-k pairs]
  __shared__ ushort mkT[384][36];   // raw mk, [true feat][s]
  __shared__ ushort gLT[64][36];    // inv-folded gated, [d][s]
  __shared__ ushort zL[384];        // permuted z (bf16)
  const int t = threadIdx.x, l = t & 63, w = t >> 6;
  const int l15 = l & 15, lq = l >> 4;
  const int bh = blockIdx.y, seg = blockIdx.x;
  const size_t rowbase = (size_t)bh * S_;
  const int mi = w >> 2, ni = w & 3;

  // z (permuted) -> LDS
  for (int cc = t; cc < DK; cc += 512) {
    int u = cc >> 7, p = (cc & 127) >> 1, par = cc & 1;
    zL[cc] = f2b(z[(size_t)bh * DK + u * 128 + par * 64 + p]);
  }

  // Wm B-frags in VGPRs (permuted k)
  const float* Wm = Wmem + (size_t)bh * (DK * DH);
  bf16x8 bw[12];
  #pragma unroll
  for (int k0i = 0; k0i < 12; k0i++) {
    bf16x8 tmp;
    #pragma unroll
    for (int j = 0; j < 8; j++) {
      int cc = k0i * 32 + lq * 8 + j;
      int u = cc >> 7, p = (cc & 127) >> 1, par = cc & 1;
      tmp[j] = (short)f2b(Wm[(size_t)(u * 128 + par * 64 + p) * DH + ni * 16 + l15]);
    }
    bw[k0i] = tmp;
  }

  f32x4 acc[3][4] = {};

  auto STAGE = [&](int ch) {
    const int pw = w >> 1, sub = w & 1;
    if (pw < 3) {
      const ushort* src = pw == 0 ? Kb : (pw == 1 ? Vb : Bgb);
      ushort* dst = pw == 0 ? &kb[0][0] : (pw == 1 ? &VL[0][0] : &BgL[0][0]);
      const size_t gbase = (rowbase + seg * 512 + ch * 32) * DH;
      #pragma unroll
      for (int j = 0; j < 2; j++) {
        int q = sub * 2 + j;
        __builtin_amdgcn_global_load_lds(
            (const AS1 u32*)(src + gbase + q * 512 + l * 8),
            (AS3 u32*)(dst + q * 512), 16, 0, 0);
      }
    }
  };

  STAGE(0);
  __syncthreads();

  for (int ch = 0; ch < 16; ch++) {
    // ---- phase 1: DPFP features (packed shuffles) ----
    float xpv[4], xnv[4];
    u32 pks[4];
    #pragma unroll
    for (int r = 0; r < 4; r++) {
      float kv = b2f(kb[w * 4 + r][l]);
      xpv[r] = fmaxf(kv, 0.f);
      xnv[r] = fmaxf(-kv, 0.f);
      pks[r] = (u32)f2b(xpv[r]) | ((u32)f2b(xnv[r]) << 16);
    }
    ushort4 mp[6];
    #pragma unroll
    for (int u = 0; u < 3; u++) {
      int ie = (l - u - 1) & 127;
      int sl = ie & 63;
      bool sw = ie >= 64;
      #pragma unroll
      for (int r = 0; r < 4; r++) {
        u32 pp = (u32)__shfl((int)pks[r], sl);
        float ps = b2f((ushort)(pp & 0xffff));
        float ns = b2f((ushort)(pp >> 16));
        float xbe = sw ? ns : ps;
        float xbo = sw ? ps : ns;
        ushort bve = f2b(xpv[r] * xbe);
        ushort bvo = f2b(xnv[r] * xbo);
        mkLd[w * 4 + r][u * 64 + l] = (u32)bve | ((u32)bvo << 16);
        ((ushort*)&mp[2 * u])[r] = bve;
        ((ushort*)&mp[2 * u + 1])[r] = bvo;
      }
    }
    #pragma unroll
    for (int tt = 0; tt < 6; tt++)
      *(ushort4*)&mkT[l + 64 * tt][w * 4] = mp[tt];
    __syncthreads();   // A: mkLd/mkT ready

    // ---- phase 2: num + Gram(ssq) + z(zs), all per-wave; then gate ----
    const ushort* mkrow = (const ushort*)&mkLd[mi * 16 + l15][0];
    f32x4 an0 = {}, an1 = {}, gacc = {}, zacc = {};
    #pragma unroll
    for (int k0i = 0; k0i < 12; k0i += 2) {
      bf16x8 afA = *(const bf16x8*)(mkrow + k0i * 32 + lq * 8);
      bf16x8 afB = *(const bf16x8*)(mkrow + (k0i + 1) * 32 + lq * 8);
      bf16x8 zfA = *(const bf16x8*)&zL[k0i * 32 + lq * 8];
      bf16x8 zfB = *(const bf16x8*)&zL[(k0i + 1) * 32 + lq * 8];
      an0 = __builtin_amdgcn_mfma_f32_16x16x32_bf16(afA, bw[k0i], an0, 0, 0, 0);
      an1 = __builtin_amdgcn_mfma_f32_16x16x32_bf16(afB, bw[k0i + 1], an1, 0, 0, 0);
      gacc = __builtin_amdgcn_mfma_f32_16x16x32_bf16(afA, afA, gacc, 0, 0, 0);
      gacc = __builtin_amdgcn_mfma_f32_16x16x32_bf16(afB, afB, gacc, 0, 0, 0);
      zacc = __builtin_amdgcn_mfma_f32_16x16x32_bf16(afA, zfA, zacc, 0, 0, 0);
      zacc = __builtin_amdgcn_mfma_f32_16x16x32_bf16(afB, zfB, zacc, 0, 0, 0);
    }
    f32x4 an = an0 + an1;
    // Gram diag -> all lanes: source lane (lq<<4) + lq*4 + rr holds C[x][x]
    float ssqv[4];
    #pragma unroll
    for (int rr = 0; rr < 4; rr++)
      ssqv[rr] = __shfl(gacc[rr], (lq << 4) + lq * 4 + rr);
    {
      ushort4 gp;
      int d = ni * 16 + l15;
      #pragma unroll
      for (int rr = 0; rr < 4; rr++) {
        int crow = mi * 16 + lq * 4 + rr;
        float inv = 1.0f / fmaxf(sqrtf(ssqv[rr]), 1e-12f);
        float rden = 1.0f / (inv * zacc[rr] + 1e-5f);
        float prev = an[rr] * inv * rden;
        float g = (b2f(VL[crow][d]) - prev) * b2f(BgL[crow][d]);
        ((ushort*)&gp)[rr] = f2b(g * inv);
      }
      *(ushort4*)&gLT[d][mi * 16 + lq * 4] = gp;
    }
    __syncthreads();   // B: gLT ready; kb/VL/BgL fully consumed

    if (ch < 15) STAGE(ch + 1);   // overlap HBM latency under assoc

    // ---- phase 3: assoc, wave owns true-feature rows [w*48, w*48+48) ----
    {
      bf16x8 bfr[4];
      #pragma unroll
      for (int n2 = 0; n2 < 4; n2++) {
        bf16x4 blo = *(const bf16x4*)&gLT[n2 * 16 + l15][lq * 8];
        bf16x4 bhi = *(const bf16x4*)&gLT[n2 * 16 + l15][lq * 8 + 4];
        bfr[n2] = __builtin_shufflevector(blo, bhi, 0, 1, 2, 3, 4, 5, 6, 7);
      }
      #pragma unroll
      for (int m2 = 0; m2 < 3; m2++) {
        bf16x4 alo = *(const bf16x4*)&mkT[w * 48 + m2 * 16 + l15][lq * 8];
        bf16x4 ahi = *(const bf16x4*)&mkT[w * 48 + m2 * 16 + l15][lq * 8 + 4];
        bf16x8 af = __builtin_shufflevector(alo, ahi, 0, 1, 2, 3, 4, 5, 6, 7);
        #pragma unroll
        for (int n2 = 0; n2 < 4; n2++)
          acc[m2][n2] = __builtin_amdgcn_mfma_f32_16x16x32_bf16(af, bfr[n2], acc[m2][n2], 0, 0, 0);
      }
    }
    __syncthreads();   // C: assoc reads done; staged loads drained
  }

  ushort* pb = part + ((size_t)bh * 4 + seg) * (DK * DH);
  #pragma unroll
  for (int m2 = 0; m2 < 3; m2++)
    #pragma unroll
    for (int n2 = 0; n2 < 4; n2++)
      #pragma unroll
      for (int rc = 0; rc < 4; rc++)
        pb[(size_t)(w * 48 + m2 * 16 + lq * 4 + rc) * DH + n2 * 16 + l15] =
            f2b(acc[m2][n2][rc]);
}

// ---------------- K3: out = Wmem + sum of 4 bf16 partials ----------------------
__global__ __launch_bounds__(256) void k_reduce(
    const float* __restrict__ Wmem, const ushort* __restrict__ part,
    float* __restrict__ out) {
  size_t i4 = (size_t)blockIdx.x * 256 + threadIdx.x;   // over 786432 float4s
  int bh = (int)(i4 / 6144);
  size_t r4 = i4 - (size_t)bh * 6144;
  float4 acc = *(const float4*)(Wmem + i4 * 4);
  #pragma unroll
  for (int k = 0; k < 4; k++) {
    const ushort* pp = part + ((size_t)bh * 4 + k) * (DK * DH) + r4 * 4;
    ushort4 pv = *(const ushort4*)pp;
    acc.x += b2f(pv.x);
    acc.y += b2f(pv.y);
    acc.z += b2f(pv.z);
    acc.w += b2f(pv.w);
  }
  *(float4*)(out + i4 * 4) = acc;
}

extern "C" void kernel_launch(void* const* d_in, const int* in_sizes, int n_in,
                              void* d_out, int out_size, void* d_ws, size_t ws_size,
                              hipStream_t stream) {
  const float* X  = (const float*)d_in[0];
  const float* Wk = (const float*)d_in[1];
  const float* Wv = (const float*)d_in[2];
  const float* Wb = (const float*)d_in[3];
  const float* Wm = (const float*)d_in[4];
  const float* z  = (const float*)d_in[5];
  float* out = (float*)d_out;
  char* ws = (char*)d_ws;

  // ws layout (~140.5 MB; ws_size >= 170 MB proven):
  //   Xb    : 0          .. 33,554,432   (dead after k_proj; part aliases)
  //   Wball : 33,554,432 .. 39,845,888
  //   kvb   : 39,845,888 .. 140,509,184  (K | V | sig(B))
  ushort* Xb    = (ushort*)(ws);
  ushort* Wball = (ushort*)(ws + 33554432ull);
  ushort* kvb   = (ushort*)(ws + 39845888ull);
  ushort* part  = (ushort*)(ws);                  // 25.2 MB, aliases dead Xb
  ushort* Kb  = kvb;
  ushort* Vb  = kvb + (size_t)B_ * H_ * S_ * DH;
  ushort* Bgb = kvb + 2ull * (size_t)B_ * H_ * S_ * DH;

  k_cvt   <<<dim3(2048), 256, 0, stream>>>(X, Wk, Wv, Wb, Xb, Wball);
  k_proj  <<<dim3(128, 8, 3), 256, 0, stream>>>(Xb, Wball, kvb);
  k_fused5<<<dim3(4, B_ * H_), 512, 0, stream>>>(Kb, Vb, Bgb, Wm, z, part);
  k_reduce<<<dim3(3072), 256, 0, stream>>>(Wm, part, out);
}

// Round 13
// 257.049 us; speedup vs baseline: 1.3170x; 1.0968x over previous
//
#include <hip/hip_runtime.h>
#include <hip/hip_bf16.h>

#define B_ 8
#define S_ 2048
#define DM 1024
#define H_ 16
#define DH 64
#define DK 384

#define AS3 __attribute__((address_space(3)))
#define AS1 __attribute__((address_space(1)))
typedef unsigned int u32;

typedef __attribute__((ext_vector_type(8))) short bf16x8;
typedef __attribute__((ext_vector_type(4))) short bf16x4;
typedef __attribute__((ext_vector_type(4))) float f32x4;

static __device__ __forceinline__ ushort f2b(float f) {
  __hip_bfloat16 h = __float2bfloat16(f);
  return *reinterpret_cast<ushort*>(&h);
}
static __device__ __forceinline__ float b2f(ushort u) {
  __hip_bfloat16 h;
  *reinterpret_cast<ushort*>(&h) = u;
  return __bfloat162float(h);
}

// ---------------- K0: convert X and Wk/Wv/Wb to bf16 (once) --------------------
__global__ __launch_bounds__(256) void k_cvt(
    const float* __restrict__ X, const float* __restrict__ Wk,
    const float* __restrict__ Wv, const float* __restrict__ Wb,
    ushort* __restrict__ Xb, ushort* __restrict__ Wball) {
  const int total = 2097152 + 3 * 131072;
  int c = blockIdx.x * 256 + threadIdx.x;
  const int stride = gridDim.x * 256;
  for (; c < total; c += stride) {
    const float* s;
    ushort* d;
    size_t off;
    if (c < 2097152) { s = X; d = Xb; off = (size_t)c; }
    else {
      int cc = c - 2097152;
      int wsel = cc >> 17;
      off = (size_t)(cc & 131071);
      s = wsel == 0 ? Wk : (wsel == 1 ? Wv : Wb);
      d = Wball + (size_t)wsel * (DM * DM);
    }
    float4 a = *(const float4*)(s + off * 8);
    float4 b = *(const float4*)(s + off * 8 + 4);
    ushort u[8] = { f2b(a.x), f2b(a.y), f2b(a.z), f2b(a.w),
                    f2b(b.x), f2b(b.y), f2b(b.z), f2b(b.w) };
    *(uint4*)(d + off * 8) = *(uint4*)u;
  }
}

// ---------------- K1: projection GEMM  Y = Xb @ Wb^T, dbuf + XCD swizzle -------
__global__ __launch_bounds__(256) void k_proj(
    const ushort* __restrict__ Xb, const ushort* __restrict__ Wball,
    ushort* __restrict__ kvb) {
  __shared__ ushort SH[4 * 8192];              // As[2] | Bs[2]  (64 KB)
  ushort* As = SH;
  ushort* Bs = SH + 2 * 8192;
  const int t = threadIdx.x, lane = t & 63, w = t >> 6;
  const int wm = w >> 1, wn = w & 1;
  const int bid = blockIdx.x + (blockIdx.y << 7) + (blockIdx.z << 10);
  const int c = bid & 7, r = bid >> 3;
  const int xb = c * 16 + (r & 15);
  const int rest = r >> 4;
  const int yb = rest & 7, zb = rest >> 3;
  const int m0 = xb * 128;
  const int n0 = yb * 128;
  const int wsel = zb;
  const ushort* Wmat = Wball + (size_t)wsel * (DM * DM);
  ushort* out = kvb + (size_t)wsel * ((size_t)B_ * H_ * S_ * DH);

  const int rowst = (lane >> 3);
  const int colsw = ((lane & 7) ^ rowst) << 3;

  auto STAGE = [&](int buf, int k0) {
    #pragma unroll
    for (int j = 0; j < 4; j++) {
      int row = (w * 4 + j) * 8 + rowst;
      __builtin_amdgcn_global_load_lds(
          (const AS1 u32*)(Xb + (size_t)(m0 + row) * DM + k0 + colsw),
          (AS3 u32*)(As + buf * 8192 + (w * 4 + j) * 512), 16, 0, 0);
      __builtin_amdgcn_global_load_lds(
          (const AS1 u32*)(Wmat + (size_t)(n0 + row) * DM + k0 + colsw),
          (AS3 u32*)(Bs + buf * 8192 + (w * 4 + j) * 512), 16, 0, 0);
    }
  };

  f32x4 acc[4][4] = {};
  STAGE(0, 0);
  __syncthreads();
  int cur = 0;
  for (int kt = 0; kt < 16; kt++) {
    if (kt < 15) STAGE(cur ^ 1, (kt + 1) * 64);
    const ushort* Ab = As + cur * 8192;
    const ushort* Bb = Bs + cur * 8192;
    #pragma unroll
    for (int kk2 = 0; kk2 < 2; kk2++) {
      const int csw = (((lane >> 4) + 4 * kk2) ^ (lane & 7)) << 3;
      bf16x8 af[4], bfr[4];
      #pragma unroll
      for (int mi = 0; mi < 4; mi++)
        af[mi] = *(const bf16x8*)&Ab[(wm * 64 + mi * 16 + (lane & 15)) * 64 + csw];
      #pragma unroll
      for (int ni = 0; ni < 4; ni++)
        bfr[ni] = *(const bf16x8*)&Bb[(wn * 64 + ni * 16 + (lane & 15)) * 64 + csw];
      #pragma unroll
      for (int mi = 0; mi < 4; mi++)
        #pragma unroll
        for (int ni = 0; ni < 4; ni++)
          acc[mi][ni] = __builtin_amdgcn_mfma_f32_16x16x32_bf16(af[mi], bfr[ni], acc[mi][ni], 0, 0, 0);
    }
    __syncthreads();
    cur ^= 1;
  }

  // Epilogue: single 128x136 LDS bounce, coalesced stores.
  ushort (*Cb)[136] = (ushort (*)[136])SH;
  #pragma unroll
  for (int mi = 0; mi < 4; mi++)
    #pragma unroll
    for (int ni = 0; ni < 4; ni++)
      #pragma unroll
      for (int rr = 0; rr < 4; rr++) {
        float val = acc[mi][ni][rr];
        if (wsel == 2) val = 1.0f / (1.0f + __expf(-val));
        Cb[wm * 64 + mi * 16 + (lane >> 4) * 4 + rr]
          [wn * 64 + ni * 16 + (lane & 15)] = f2b(val);
      }
  __syncthreads();
  #pragma unroll
  for (int q = 0; q < 8; q++) {
    int idx = q * 256 + t;
    int lm = idx >> 4;
    int c16 = idx & 15;
    int m = m0 + lm;
    int b = m >> 11, s = m & 2047;
    int o0 = n0 + c16 * 8;
    int h = o0 >> 6, d = o0 & 63;
    *(uint4*)(out + (((size_t)(b * H_ + h)) * S_ + s) * DH + d) =
        *(uint4*)&Cb[lm][c16 * 8];
  }
}

// ---------------- K2: fused DPFP + num + gate + assoc (register streaming) -----
// grid (4, 128), 512 threads. K/V/Bg go straight to registers (no staging LDS);
// mkLd is XOR-swizzled (conflict-free, unpadded). 3 barriers/chunk.
__global__ __launch_bounds__(512) void k_fused6(
    const ushort* __restrict__ Kb, const ushort* __restrict__ Vb,
    const ushort* __restrict__ Bgb, const float* __restrict__ Wmem,
    const float* __restrict__ z, ushort* __restrict__ part) {
  __shared__ u32 mkLd[32][192];     // raw mk, perm-k pairs, XOR-swizzled (24 KB)
  __shared__ ushort mkT[384][36];   // raw mk, [true feat][s] (27.6 KB)
  __shared__ ushort gLT[64][36];    // inv-folded gated, [d][s] (4.6 KB)
  __shared__ ushort zL[384];        // permuted z (bf16)
  const int t = threadIdx.x, l = t & 63, w = t >> 6;
  const int l15 = l & 15, lq = l >> 4;
  const int bh = blockIdx.y, seg = blockIdx.x;
  const size_t rowbase = (size_t)bh * S_;
  const int mi = w >> 2, ni = w & 3;
  const int dcol = ni * 16 + l15;

  // z (permuted) -> LDS
  for (int cc = t; cc < DK; cc += 512) {
    int u = cc >> 7, p = (cc & 127) >> 1, par = cc & 1;
    zL[cc] = f2b(z[(size_t)bh * DK + u * 128 + par * 64 + p]);
  }

  // Wm B-frags in VGPRs (permuted k)
  const float* Wm = Wmem + (size_t)bh * (DK * DH);
  bf16x8 bw[12];
  #pragma unroll
  for (int k0i = 0; k0i < 12; k0i++) {
    bf16x8 tmp;
    #pragma unroll
    for (int j = 0; j < 8; j++) {
      int cc = k0i * 32 + lq * 8 + j;
      int u = cc >> 7, p = (cc & 127) >> 1, par = cc & 1;
      tmp[j] = (short)f2b(Wm[(size_t)(u * 128 + par * 64 + p) * DH + dcol]);
    }
    bw[k0i] = tmp;
  }

  f32x4 acc[3][4] = {};
  ushort kreg[4], vreg[4], breg[4];

  auto LOADCH = [&](int ch) {
    const int s0 = seg * 512 + ch * 32;
    #pragma unroll
    for (int r = 0; r < 4; r++)
      kreg[r] = Kb[(rowbase + s0 + w * 4 + r) * DH + l];
    #pragma unroll
    for (int rr = 0; rr < 4; rr++) {
      size_t ga = (rowbase + s0 + mi * 16 + lq * 4 + rr) * DH + dcol;
      vreg[rr] = Vb[ga];
      breg[rr] = Bgb[ga];
    }
  };

  LOADCH(0);
  __syncthreads();   // zL ready

  for (int ch = 0; ch < 16; ch++) {
    // ---- phase 1: DPFP (registers + shuffles), write mkLd(swz)/mkT ----
    float xpv[4], xnv[4];
    u32 pks[4];
    #pragma unroll
    for (int r = 0; r < 4; r++) {
      float kv = b2f(kreg[r]);
      xpv[r] = fmaxf(kv, 0.f);
      xnv[r] = fmaxf(-kv, 0.f);
      pks[r] = (u32)f2b(xpv[r]) | ((u32)f2b(xnv[r]) << 16);
    }
    ushort4 mp[6];
    #pragma unroll
    for (int u = 0; u < 3; u++) {
      int ie = (l - u - 1) & 127;
      int sl = ie & 63;
      bool sw = ie >= 64;
      #pragma unroll
      for (int r = 0; r < 4; r++) {
        u32 pp = (u32)__shfl((int)pks[r], sl);
        float ps = b2f((ushort)(pp & 0xffff));
        float ns = b2f((ushort)(pp >> 16));
        float xbe = sw ? ns : ps;
        float xbo = sw ? ps : ns;
        ushort bve = f2b(xpv[r] * xbe);
        ushort bvo = f2b(xnv[r] * xbo);
        int row = w * 4 + r;
        mkLd[row][(u * 64 + l) ^ ((row & 7) << 2)] = (u32)bve | ((u32)bvo << 16);
        ((ushort*)&mp[2 * u])[r] = bve;
        ((ushort*)&mp[2 * u + 1])[r] = bvo;
      }
    }
    #pragma unroll
    for (int tt = 0; tt < 6; tt++)
      *(ushort4*)&mkT[l + 64 * tt][w * 4] = mp[tt];
    __syncthreads();   // A: mkLd/mkT ready

    // ---- phase 2: num + Gram(ssq) + z(zs) per-wave; gate -> gLT ----
    const u32* mkrow = &mkLd[mi * 16 + l15][0];
    const int xr = (l15 & 7) << 2;
    f32x4 an0 = {}, an1 = {}, gacc = {}, zacc = {};
    #pragma unroll
    for (int k0i = 0; k0i < 12; k0i += 2) {
      bf16x8 afA = *(const bf16x8*)(mkrow + ((k0i * 16 + lq * 4) ^ xr));
      bf16x8 afB = *(const bf16x8*)(mkrow + (((k0i + 1) * 16 + lq * 4) ^ xr));
      bf16x8 zfA = *(const bf16x8*)&zL[k0i * 32 + lq * 8];
      bf16x8 zfB = *(const bf16x8*)&zL[(k0i + 1) * 32 + lq * 8];
      an0 = __builtin_amdgcn_mfma_f32_16x16x32_bf16(afA, bw[k0i], an0, 0, 0, 0);
      an1 = __builtin_amdgcn_mfma_f32_16x16x32_bf16(afB, bw[k0i + 1], an1, 0, 0, 0);
      gacc = __builtin_amdgcn_mfma_f32_16x16x32_bf16(afA, afA, gacc, 0, 0, 0);
      gacc = __builtin_amdgcn_mfma_f32_16x16x32_bf16(afB, afB, gacc, 0, 0, 0);
      zacc = __builtin_amdgcn_mfma_f32_16x16x32_bf16(afA, zfA, zacc, 0, 0, 0);
      zacc = __builtin_amdgcn_mfma_f32_16x16x32_bf16(afB, zfB, zacc, 0, 0, 0);
    }
    f32x4 an = an0 + an1;
    float ssqv[4];
    #pragma unroll
    for (int rr = 0; rr < 4; rr++)
      ssqv[rr] = __shfl(gacc[rr], (lq << 4) + lq * 4 + rr);
    {
      ushort4 gp;
      #pragma unroll
      for (int rr = 0; rr < 4; rr++) {
        float inv = 1.0f / fmaxf(sqrtf(ssqv[rr]), 1e-12f);
        float rden = 1.0f / (inv * zacc[rr] + 1e-5f);
        float prev = an[rr] * inv * rden;
        float g = (b2f(vreg[rr]) - prev) * b2f(breg[rr]);
        ((ushort*)&gp)[rr] = f2b(g * inv);
      }
      *(ushort4*)&gLT[dcol][mi * 16 + lq * 4] = gp;
    }
    __syncthreads();   // B: gLT ready

    if (ch < 15) LOADCH(ch + 1);   // prefetch next chunk under assoc

    // ---- phase 3: assoc, wave owns true-feature rows [w*48, w*48+48) ----
    {
      bf16x8 bfr[4];
      #pragma unroll
      for (int n2 = 0; n2 < 4; n2++) {
        bf16x4 blo = *(const bf16x4*)&gLT[n2 * 16 + l15][lq * 8];
        bf16x4 bhi = *(const bf16x4*)&gLT[n2 * 16 + l15][lq * 8 + 4];
        bfr[n2] = __builtin_shufflevector(blo, bhi, 0, 1, 2, 3, 4, 5, 6, 7);
      }
      #pragma unroll
      for (int m2 = 0; m2 < 3; m2++) {
        bf16x4 alo = *(const bf16x4*)&mkT[w * 48 + m2 * 16 + l15][lq * 8];
        bf16x4 ahi = *(const bf16x4*)&mkT[w * 48 + m2 * 16 + l15][lq * 8 + 4];
        bf16x8 af = __builtin_shufflevector(alo, ahi, 0, 1, 2, 3, 4, 5, 6, 7);
        #pragma unroll
        for (int n2 = 0; n2 < 4; n2++)
          acc[m2][n2] = __builtin_amdgcn_mfma_f32_16x16x32_bf16(af, bfr[n2], acc[m2][n2], 0, 0, 0);
      }
    }
    __syncthreads();   // C: assoc reads done before next phase-1 writes
  }

  ushort* pb = part + ((size_t)bh * 4 + seg) * (DK * DH);
  #pragma unroll
  for (int m2 = 0; m2 < 3; m2++)
    #pragma unroll
    for (int n2 = 0; n2 < 4; n2++)
      #pragma unroll
      for (int rc = 0; rc < 4; rc++)
        pb[(size_t)(w * 48 + m2 * 16 + lq * 4 + rc) * DH + n2 * 16 + l15] =
            f2b(acc[m2][n2][rc]);
}

// ---------------- K3: out = Wmem + sum of 4 bf16 partials ----------------------
__global__ __launch_bounds__(256) void k_reduce(
    const float* __restrict__ Wmem, const ushort* __restrict__ part,
    float* __restrict__ out) {
  size_t i4 = (size_t)blockIdx.x * 256 + threadIdx.x;
  int bh = (int)(i4 / 6144);
  size_t r4 = i4 - (size_t)bh * 6144;
  float4 acc = *(const float4*)(Wmem + i4 * 4);
  #pragma unroll
  for (int k = 0; k < 4; k++) {
    const ushort* pp = part + ((size_t)bh * 4 + k) * (DK * DH) + r4 * 4;
    ushort4 pv = *(const ushort4*)pp;
    acc.x += b2f(pv.x);
    acc.y += b2f(pv.y);
    acc.z += b2f(pv.z);
    acc.w += b2f(pv.w);
  }
  *(float4*)(out + i4 * 4) = acc;
}

extern "C" void kernel_launch(void* const* d_in, const int* in_sizes, int n_in,
                              void* d_out, int out_size, void* d_ws, size_t ws_size,
                              hipStream_t stream) {
  const float* X  = (const float*)d_in[0];
  const float* Wk = (const float*)d_in[1];
  const float* Wv = (const float*)d_in[2];
  const float* Wb = (const float*)d_in[3];
  const float* Wm = (const float*)d_in[4];
  const float* z  = (const float*)d_in[5];
  float* out = (float*)d_out;
  char* ws = (char*)d_ws;

  // ws layout (~140.5 MB; ws_size >= 170 MB proven):
  //   Xb    : 0          .. 33,554,432   (dead after k_proj; part aliases)
  //   Wball : 33,554,432 .. 39,845,888
  //   kvb   : 39,845,888 .. 140,509,184  (K | V | sig(B))
  ushort* Xb    = (ushort*)(ws);
  ushort* Wball = (ushort*)(ws + 33554432ull);
  ushort* kvb   = (ushort*)(ws + 39845888ull);
  ushort* part  = (ushort*)(ws);                  // 25.2 MB, aliases dead Xb
  ushort* Kb  = kvb;
  ushort* Vb  = kvb + (size_t)B_ * H_ * S_ * DH;
  ushort* Bgb = kvb + 2ull * (size_t)B_ * H_ * S_ * DH;

  k_cvt   <<<dim3(2048), 256, 0, stream>>>(X, Wk, Wv, Wb, Xb, Wball);
  k_proj  <<<dim3(128, 8, 3), 256, 0, stream>>>(Xb, Wball, kvb);
  k_fused6<<<dim3(4, B_ * H_), 512, 0, stream>>>(Kb, Vb, Bgb, Wm, z, part);
  k_reduce<<<dim3(3072), 256, 0, stream>>>(Wm, part, out);
}